// Round 11
// baseline (317.877 us; speedup 1.0000x reference)
//
#include <hip/hip_runtime.h>
#include <hip/hip_bf16.h>

#define CH 128          // HID_CH == OUT_CH == 128
#define IN_CH_K 512
#define CHUNK 2048      // edges per bucket-sort block (782 blocks -> ~3/CU)
#define BPAD 5120       // padded per-bucket capacity (expect ~4096, 16-sigma margin)

typedef short s16x8 __attribute__((ext_vector_type(8)));   // 8 bf16 (4 VGPRs)
typedef float f32x4 __attribute__((ext_vector_type(4)));

__device__ __forceinline__ unsigned int f2bf(float f) {
    unsigned int u = __builtin_bit_cast(unsigned int, f);
    return (u + 0x7fffu + ((u >> 16) & 1u)) >> 16;
}
// packed f32x2 -> bf16x2 via HW cvt (RNE, same bits as f2bf)
__device__ __forceinline__ unsigned int pk2bf(float lo, float hi) {
    unsigned int r;
    asm("v_cvt_pk_bf16_f32 %0, %1, %2" : "=v"(r) : "v"(lo), "v"(hi));
    return r;
}
__device__ __forceinline__ float bf_lo(unsigned int u) {
    return __builtin_bit_cast(float, u << 16);
}
__device__ __forceinline__ float bf_hi(unsigned int u) {
    return __builtin_bit_cast(float, u & 0xFFFF0000u);
}
// relu on 2 packed bf16: zero each 16-bit half whose sign bit is set
__device__ __forceinline__ unsigned int relu_pk(unsigned int w) {
    unsigned int keep = (~w) & 0x80008000u;
    unsigned int mask = keep - (keep >> 15);
    return w & mask;
}

// ---------------- streaming f32 -> bf16 conversion of x (also a BW probe) ----------------
// fill-like: grid-stride, 32B read + 16B write per thread-iter, ~8 VGPR, max TLP.
__global__ void convert_x_kernel(const float4* __restrict__ x4, uint4* __restrict__ xbf,
                                 int ngroups) {
    int i = blockIdx.x * blockDim.x + threadIdx.x;
    const int stride = gridDim.x * blockDim.x;
    for (int g = i; g < ngroups; g += stride) {
        float4 f0 = x4[(size_t)g * 2];
        float4 f1 = x4[(size_t)g * 2 + 1];
        uint4 pk;
        pk.x = pk2bf(f0.x, f0.y);
        pk.y = pk2bf(f0.z, f0.w);
        pk.z = pk2bf(f1.x, f1.y);
        pk.w = pk2bf(f1.z, f1.w);
        xbf[g] = pk;
    }
}

// ---------------- bucket-sort CSR build ----------------
__global__ void init_cursor_kernel(int* __restrict__ cursor, int NB) {
    int i = blockIdx.x * blockDim.x + threadIdx.x;
    if (i < NB) cursor[i] = i * BPAD;
}

// bin edges into padded bucket regions; per-edge cursors in LDS, one global atomic per (block,bucket)
__global__ void bin_kernel(const int* __restrict__ src, const int* __restrict__ dst,
                           int* __restrict__ cursor, int* __restrict__ binned,
                           int E, int NB) {
    __shared__ int h[512];
    __shared__ int base[512];
    __shared__ int cur[512];
    const int tid = threadIdx.x;
    for (int i = tid; i < NB; i += 256) h[i] = 0;
    __syncthreads();

    const int E4 = E >> 2;
    const int beg4 = blockIdx.x * (CHUNK / 4);
    const int end4 = min(E4, beg4 + CHUNK / 4);
    const int4* dst4 = reinterpret_cast<const int4*>(dst);
    const int4* src4 = reinterpret_cast<const int4*>(src);
    const bool last = (blockIdx.x == gridDim.x - 1);

    for (int e4 = beg4 + tid; e4 < end4; e4 += 256) {
        int4 d = dst4[e4];
        atomicAdd(&h[d.x >> 8], 1);
        atomicAdd(&h[d.y >> 8], 1);
        atomicAdd(&h[d.z >> 8], 1);
        atomicAdd(&h[d.w >> 8], 1);
    }
    if (last) {
        for (int e = (E & ~3) + tid; e < E; e += 256)
            atomicAdd(&h[dst[e] >> 8], 1);
    }
    __syncthreads();
    for (int i = tid; i < NB; i += 256) {
        cur[i] = 0;
        if (h[i]) base[i] = atomicAdd(&cursor[i], h[i]);
    }
    __syncthreads();

    for (int e4 = beg4 + tid; e4 < end4; e4 += 256) {
        int4 d = dst4[e4];
        int4 s = src4[e4];
        int b, r, idx;
        b = d.x >> 8; r = atomicAdd(&cur[b], 1); idx = base[b] + r;
        if (idx < (b + 1) * BPAD) binned[idx] = s.x | ((d.x & 255) << 17);
        b = d.y >> 8; r = atomicAdd(&cur[b], 1); idx = base[b] + r;
        if (idx < (b + 1) * BPAD) binned[idx] = s.y | ((d.y & 255) << 17);
        b = d.z >> 8; r = atomicAdd(&cur[b], 1); idx = base[b] + r;
        if (idx < (b + 1) * BPAD) binned[idx] = s.z | ((d.z & 255) << 17);
        b = d.w >> 8; r = atomicAdd(&cur[b], 1); idx = base[b] + r;
        if (idx < (b + 1) * BPAD) binned[idx] = s.w | ((d.w & 255) << 17);
    }
    if (last) {
        for (int e = (E & ~3) + tid; e < E; e += 256) {
            int d = dst[e];
            int b = d >> 8;
            int r = atomicAdd(&cur[b], 1);
            int idx = base[b] + r;
            if (idx < (b + 1) * BPAD) binned[idx] = src[e] | ((d & 255) << 17);
        }
    }
}

// per-bucket (256 nodes) CSR finalize: row ranges, dinv, csr_src; per-edge atomics in LDS
__global__ void csr_bucket_kernel(const int* __restrict__ binned, const int* __restrict__ cursor,
                                  int2* __restrict__ row_range, int* __restrict__ csr_src,
                                  float* __restrict__ dinv, int N) {
    __shared__ int cnt[256];
    __shared__ int off[256];
    __shared__ int cur[256];
    const int k = blockIdx.x;
    const int t = threadIdx.x;
    cnt[t] = 0;
    __syncthreads();
    const int beg = k * BPAD;
    const int end = min(cursor[k], (k + 1) * BPAD);
    const int nv = (end - beg) & ~3;        // vectorizable count (beg is 16B-aligned)
    const int4* b4 = reinterpret_cast<const int4*>(binned + beg);

    for (int q = t; q * 4 < nv; q += 256) {
        int4 p = b4[q];
        atomicAdd(&cnt[p.x >> 17], 1);
        atomicAdd(&cnt[p.y >> 17], 1);
        atomicAdd(&cnt[p.z >> 17], 1);
        atomicAdd(&cnt[p.w >> 17], 1);
    }
    for (int e = beg + nv + t; e < end; e += 256)
        atomicAdd(&cnt[binned[e] >> 17], 1);
    __syncthreads();
    int v = cnt[t];
    off[t] = v;
    __syncthreads();
    #pragma unroll
    for (int o = 1; o < 256; o <<= 1) {
        int tv = (t >= o) ? off[t - o] : 0;
        __syncthreads();
        off[t] += tv;
        __syncthreads();
    }
    int ex = off[t] - v;
    int node = k * 256 + t;
    if (node < N) {
        row_range[node] = make_int2(beg + ex, beg + ex + v);
        dinv[node] = rsqrtf((float)(v + 1));   // +1 self-loop
    }
    cur[t] = ex;
    __syncthreads();
    for (int q = t; q * 4 < nv; q += 256) {
        int4 p = b4[q];
        int dl, r;
        dl = p.x >> 17; r = atomicAdd(&cur[dl], 1); csr_src[beg + r] = p.x & 0x1FFFF;
        dl = p.y >> 17; r = atomicAdd(&cur[dl], 1); csr_src[beg + r] = p.y & 0x1FFFF;
        dl = p.z >> 17; r = atomicAdd(&cur[dl], 1); csr_src[beg + r] = p.z & 0x1FFFF;
        dl = p.w >> 17; r = atomicAdd(&cur[dl], 1); csr_src[beg + r] = p.w & 0x1FFFF;
    }
    for (int e = beg + nv + t; e < end; e += 256) {
        int p = binned[e];
        int dl = p >> 17;
        int r = atomicAdd(&cur[dl], 1);
        csr_src[beg + r] = p & 0x1FFFF;
    }
}

// ---------------- weight pre-transpose to MFMA B-fragment layout ----------------
// WT[g*128 + col] (uint4 = 8 bf16) holds W[k(g*8+j)][col], j=0..7.
// PERM: storage k' -> true k = (k'>>3) + ((k'&7)<<4)  (layer 2: A cols are permuted)
template<bool PERM>
__global__ void convert_w_kernel(const float* __restrict__ W, uint4* __restrict__ WT, int K) {
    int i = blockIdx.x * blockDim.x + threadIdx.x;
    int ng = K >> 3;
    if (i >= ng * CH) return;
    int g = i >> 7;
    int col = i & 127;
    unsigned int h[8];
    #pragma unroll
    for (int j = 0; j < 8; ++j) {
        int kp = g * 8 + j;
        int k = PERM ? ((kp >> 3) + ((kp & 7) << 4)) : kp;
        h[j] = f2bf(W[(size_t)k * CH + col]);
    }
    uint4 v;
    v.x = h[0] | (h[1] << 16);
    v.y = h[2] | (h[3] << 16);
    v.z = h[4] | (h[5] << 16);
    v.w = h[6] | (h[7] << 16);
    WT[i] = v;
}

// ---------------- GEMM1: g1[M][128](bf16, permuted cols) = (xbf[M][512] @ W1) * dinv[row] ----------------
// A is pre-converted bf16 (convert_x_kernel). Stage: wave reads one FULL 1KB row per iter
// (64 lanes x 16B contiguous), one swizzled ds_write_b128. Compute: swizzled ds_read_b128
// per k-step (2-way conflict = free), B prefetched 1-deep from L2.
// storage col' = l15*8 + n  (true col = n*16 + l15)
__launch_bounds__(256, 2)
__global__ void gemm1_mfma_kernel(const uint4* __restrict__ XB, const uint4* __restrict__ WT,
                                  const float* __restrict__ dinv, unsigned short* __restrict__ C,
                                  int M) {
    __shared__ uint4 As[64 * 64];   // [local row][granule of 8 bf16], swizzled

    const int tid = threadIdx.x;
    const int wid = tid >> 6;
    const int lane = tid & 63;
    const int block_row = blockIdx.x * 64;

    // ---- stage: iter it -> wave wid loads local row it*4+wid (1KB contiguous) ----
    #pragma unroll
    for (int it = 0; it < 16; ++it) {
        const int lr = it * 4 + wid;
        const int grow = min(block_row + lr, M - 1);
        uint4 v = XB[(size_t)grow * 64 + lane];
        As[lr * 64 + (lane ^ (lr & 7))] = v;
    }
    __syncthreads();

    const int l15 = lane & 15;
    const int lg = lane >> 4;
    const int lr = wid * 16 + l15;                  // local row this lane computes
    const int wave_row = block_row + wid * 16;
    const uint4* wp = WT + (size_t)lg * CH + l15;   // +4*CH per k-step; +16*n per frag

    f32x4 acc[8];
    #pragma unroll
    for (int n = 0; n < 8; ++n) acc[n] = (f32x4){0.f, 0.f, 0.f, 0.f};

    // ---- B prologue (k-step 0) ----
    uint4 bw[8];
    #pragma unroll
    for (int n = 0; n < 8; ++n) bw[n] = wp[n * 16];

    #pragma unroll
    for (int ks = 0; ks < 16; ++ks) {
        // 1-deep B prefetch (L2-resident)
        uint4 nbw[8];
        if (ks < 15) {
            const uint4* nwp = wp + (size_t)(ks + 1) * 4 * CH;
            #pragma unroll
            for (int n = 0; n < 8; ++n) nbw[n] = nwp[n * 16];
        }

        // A fragment from swizzled LDS
        uint4 av = As[lr * 64 + ((ks * 4 + lg) ^ (lr & 7))];
        s16x8 af = __builtin_bit_cast(s16x8, av);

        #pragma unroll
        for (int n = 0; n < 8; ++n) {
            s16x8 b = __builtin_bit_cast(s16x8, bw[n]);
            acc[n] = __builtin_amdgcn_mfma_f32_16x16x32_bf16(af, b, acc[n], 0, 0, 0);
        }

        if (ks < 15) {
            #pragma unroll
            for (int n = 0; n < 8; ++n) bw[n] = nbw[n];
        }
    }

    // ---- epilogue: D[row=lg*4+i][col=l15] per frag; scale by dinv[row]; permuted bf16 store ----
    #pragma unroll
    for (int i = 0; i < 4; ++i) {
        int row = wave_row + lg * 4 + i;
        if (row < M) {
            float s = dinv[row];
            uint4 v;
            v.x = pk2bf(acc[0][i] * s, acc[1][i] * s);
            v.y = pk2bf(acc[2][i] * s, acc[3][i] * s);
            v.z = pk2bf(acc[4][i] * s, acc[5][i] * s);
            v.w = pk2bf(acc[6][i] * s, acc[7][i] * s);
            *reinterpret_cast<uint4*>(&C[(size_t)row * CH + l15 * 8]) = v;
        }
    }
}

// ---------------- GEMM2: g2 = (relu(a1)[M][128] @ W2) * dinv[row], all bf16 permuted ----------------
__launch_bounds__(256)
__global__ void gemm2_mfma_kernel(const unsigned short* __restrict__ A, const uint4* __restrict__ WT,
                                  const float* __restrict__ dinv, unsigned short* __restrict__ C,
                                  int M) {
    const int tid = threadIdx.x;
    const int wid = tid >> 6;
    const int lane = tid & 63;
    const int l15 = lane & 15;
    const int lg = lane >> 4;

    const int block_row = blockIdx.x * 128 + wid * 32;

    f32x4 acc[2][8];
    #pragma unroll
    for (int m = 0; m < 2; ++m)
        #pragma unroll
        for (int n = 0; n < 8; ++n)
            acc[m][n] = (f32x4){0.f, 0.f, 0.f, 0.f};

    int arow0 = min(block_row + l15, M - 1);
    int arow1 = min(block_row + 16 + l15, M - 1);
    const uint4* ap0 = reinterpret_cast<const uint4*>(A + (size_t)arow0 * CH);
    const uint4* ap1 = reinterpret_cast<const uint4*>(A + (size_t)arow1 * CH);

    #pragma unroll
    for (int k0 = 0; k0 < CH; k0 += 32) {
        const int fi = (k0 >> 3) + lg;
        uint4 r0 = ap0[fi];
        uint4 r1 = ap1[fi];
        r0.x = relu_pk(r0.x); r0.y = relu_pk(r0.y); r0.z = relu_pk(r0.z); r0.w = relu_pk(r0.w);
        r1.x = relu_pk(r1.x); r1.y = relu_pk(r1.y); r1.z = relu_pk(r1.z); r1.w = relu_pk(r1.w);
        s16x8 a0 = __builtin_bit_cast(s16x8, r0);
        s16x8 a1 = __builtin_bit_cast(s16x8, r1);
        #pragma unroll
        for (int n = 0; n < 8; ++n) {
            uint4 bv = WT[(size_t)fi * CH + n * 16 + l15];
            s16x8 b = __builtin_bit_cast(s16x8, bv);
            acc[0][n] = __builtin_amdgcn_mfma_f32_16x16x32_bf16(a0, b, acc[0][n], 0, 0, 0);
            acc[1][n] = __builtin_amdgcn_mfma_f32_16x16x32_bf16(a1, b, acc[1][n], 0, 0, 0);
        }
    }

    #pragma unroll
    for (int m = 0; m < 2; ++m) {
        #pragma unroll
        for (int i = 0; i < 4; ++i) {
            int row = block_row + m * 16 + lg * 4 + i;
            if (row < M) {
                float s = dinv[row];
                uint4 v;
                v.x = pk2bf(acc[m][0][i] * s, acc[m][1][i] * s);
                v.y = pk2bf(acc[m][2][i] * s, acc[m][3][i] * s);
                v.z = pk2bf(acc[m][4][i] * s, acc[m][5][i] * s);
                v.w = pk2bf(acc[m][6][i] * s, acc[m][7][i] * s);
                *reinterpret_cast<uint4*>(&C[(size_t)row * CH + l15 * 8]) = v;
            }
        }
    }
}

// ---------------- aggregation: out[d] = dinv[d]*(g[d] + sum g[src]) + bias ----------------
// g is bf16 permuted-col [node][128]; one wave per node, 1 uint (2 bf16) per lane.
// 8-deep software-pipelined gather: next batch's indices load while current gathers fly.
#define GATHER(cc) g[(size_t)__builtin_amdgcn_readfirstlane(cc) * 64 + lane]
template<bool OUT_BF16>
__launch_bounds__(256)
__global__ void aggregate_kernel(const unsigned int* __restrict__ g, const int2* __restrict__ row_range,
                                 const int* __restrict__ csr_src, const float* __restrict__ dinv,
                                 const float* __restrict__ bias, void* __restrict__ outp, int N) {
    const int gtid = blockIdx.x * blockDim.x + threadIdx.x;
    const int node = gtid >> 6;
    if (node >= N) return;
    const int lane = threadIdx.x & 63;

    unsigned int su = g[(size_t)node * 64 + lane];   // self-loop term
    const int2 rr = row_range[node];
    float ax = bf_lo(su);
    float ay = bf_hi(su);

    int j = rr.x;
    const int end = rr.y;

    if (j + 8 <= end) {
        int c0 = csr_src[j], c1 = csr_src[j+1], c2 = csr_src[j+2], c3 = csr_src[j+3];
        int c4 = csr_src[j+4], c5 = csr_src[j+5], c6 = csr_src[j+6], c7 = csr_src[j+7];
        j += 8;
        while (j + 8 <= end) {
            int n0 = csr_src[j], n1 = csr_src[j+1], n2 = csr_src[j+2], n3 = csr_src[j+3];
            int n4 = csr_src[j+4], n5 = csr_src[j+5], n6 = csr_src[j+6], n7 = csr_src[j+7];
            j += 8;
            unsigned int u0 = GATHER(c0), u1 = GATHER(c1), u2 = GATHER(c2), u3 = GATHER(c3);
            unsigned int u4 = GATHER(c4), u5 = GATHER(c5), u6 = GATHER(c6), u7 = GATHER(c7);
            ax += ((bf_lo(u0) + bf_lo(u1)) + (bf_lo(u2) + bf_lo(u3)))
                + ((bf_lo(u4) + bf_lo(u5)) + (bf_lo(u6) + bf_lo(u7)));
            ay += ((bf_hi(u0) + bf_hi(u1)) + (bf_hi(u2) + bf_hi(u3)))
                + ((bf_hi(u4) + bf_hi(u5)) + (bf_hi(u6) + bf_hi(u7)));
            c0 = n0; c1 = n1; c2 = n2; c3 = n3;
            c4 = n4; c5 = n5; c6 = n6; c7 = n7;
        }
        unsigned int u0 = GATHER(c0), u1 = GATHER(c1), u2 = GATHER(c2), u3 = GATHER(c3);
        unsigned int u4 = GATHER(c4), u5 = GATHER(c5), u6 = GATHER(c6), u7 = GATHER(c7);
        ax += ((bf_lo(u0) + bf_lo(u1)) + (bf_lo(u2) + bf_lo(u3)))
            + ((bf_lo(u4) + bf_lo(u5)) + (bf_lo(u6) + bf_lo(u7)));
        ay += ((bf_hi(u0) + bf_hi(u1)) + (bf_hi(u2) + bf_hi(u3)))
            + ((bf_hi(u4) + bf_hi(u5)) + (bf_hi(u6) + bf_hi(u7)));
    }
    for (; j + 2 <= end; j += 2) {
        int c0 = csr_src[j], c1 = csr_src[j+1];
        unsigned int u0 = GATHER(c0), u1 = GATHER(c1);
        ax += bf_lo(u0) + bf_lo(u1);
        ay += bf_hi(u0) + bf_hi(u1);
    }
    if (j < end) {
        int c0 = csr_src[j];
        unsigned int u0 = GATHER(c0);
        ax += bf_lo(u0);
        ay += bf_hi(u0);
    }

    const int cp0 = lane << 1;
    const int cp1 = cp0 | 1;
    const int c0 = (cp0 >> 3) + ((cp0 & 7) << 4);    // true cols
    const int c1 = (cp1 >> 3) + ((cp1 & 7) << 4);
    const float di = dinv[node];
    float ox = di * ax + bias[c0];
    float oy = di * ay + bias[c1];
    if (OUT_BF16) {
        ((unsigned int*)outp)[(size_t)node * 64 + lane] = pk2bf(ox, oy);
    } else {
        float* o = (float*)outp + (size_t)node * CH;
        o[c0] = ox;
        o[c1] = oy;
    }
}

extern "C" void kernel_launch(void* const* d_in, const int* in_sizes, int n_in,
                              void* d_out, int out_size, void* d_ws, size_t ws_size,
                              hipStream_t stream) {
    const float* x  = (const float*)d_in[0];
    const int*   ei = (const int*)d_in[1];
    const float* W1 = (const float*)d_in[2];
    const float* b1 = (const float*)d_in[3];
    const float* W2 = (const float*)d_in[4];
    const float* b2 = (const float*)d_in[5];
    float* out = (float*)d_out;

    const int N = in_sizes[0] / IN_CH_K;       // 100000
    const int E = in_sizes[1] / 2;             // 1600000
    const int* e_src = ei;
    const int* e_dst = ei + E;

    const int NB = (N + 255) >> 8;             // 391 coarse buckets
    const int NCHUNK = (E + CHUNK - 1) / CHUNK;

    char* w = (char*)d_ws;
    auto alloc = [&](size_t bytes) {
        char* p = w;
        w += (bytes + 255) & ~(size_t)255;
        return p;
    };
    int*   cursor    = (int*)  alloc((size_t)NB * 4);
    int2*  row_range = (int2*) alloc((size_t)N * 8);
    float* dinv      = (float*)alloc((size_t)N * 4);
    int*   csr_src   = (int*)  alloc((size_t)NB * BPAD * 4);
    uint4* w1t       = (uint4*)alloc((size_t)(IN_CH_K / 8) * CH * 16);
    uint4* w2t       = (uint4*)alloc((size_t)(CH / 8) * CH * 16);
    uint4* xbf       = (uint4*)alloc((size_t)N * IN_CH_K * 2);          // bf16 x, 102 MB
    unsigned short* gbuf = (unsigned short*)alloc((size_t)N * CH * 2);  // g1 / g2
    unsigned short* abuf = (unsigned short*)alloc((size_t)N * CH * 2);  // a1
    int* binned = (int*)gbuf;   // aliases gbuf (8 MB < 25.6 MB): dead before gemm1 writes

    // ---- CSR build (padded bucket sort) + weight/x conversion ----
    init_cursor_kernel<<<(NB + 255) / 256, 256, 0, stream>>>(cursor, NB);
    bin_kernel<<<NCHUNK, 256, 0, stream>>>(e_src, e_dst, cursor, binned, E, NB);
    csr_bucket_kernel<<<NB, 256, 0, stream>>>(binned, cursor, row_range, csr_src, dinv, N);
    convert_w_kernel<false><<<(IN_CH_K / 8 * CH + 255) / 256, 256, 0, stream>>>(W1, w1t, IN_CH_K);
    convert_w_kernel<true><<<(CH / 8 * CH + 255) / 256, 256, 0, stream>>>(W2, w2t, CH);
    convert_x_kernel<<<2048, 256, 0, stream>>>((const float4*)x, xbf, N * (IN_CH_K / 8));

    const int gemm1_grid = (N + 63) / 64;      // 64 rows per block (4 waves x 16 rows)
    const int gemm2_grid = (N + 127) / 128;
    const int agg_grid = (N * 64 + 255) / 256;

    // ---- layer 1 ----
    gemm1_mfma_kernel<<<gemm1_grid, 256, 0, stream>>>(xbf, w1t, dinv, gbuf, N);
    aggregate_kernel<true><<<agg_grid, 256, 0, stream>>>((const unsigned int*)gbuf, row_range,
                                                         csr_src, dinv, b1, abuf, N);

    // ---- layer 2 ----
    gemm2_mfma_kernel<<<gemm2_grid, 256, 0, stream>>>(abuf, w2t, dinv, gbuf, N);
    aggregate_kernel<false><<<agg_grid, 256, 0, stream>>>((const unsigned int*)gbuf, row_range,
                                                          csr_src, dinv, b2, out, N);
}

// Round 13
// 280.976 us; speedup vs baseline: 1.1313x; 1.1313x over previous
//
#include <hip/hip_runtime.h>
#include <hip/hip_bf16.h>

#define CH 128          // HID_CH == OUT_CH == 128
#define IN_CH_K 512
#define CHUNK 2048      // edges per bucket-sort block (782 blocks -> ~3/CU)
#define BPAD 5120       // padded per-bucket capacity (expect ~4096, 16-sigma margin)

typedef short s16x8 __attribute__((ext_vector_type(8)));   // 8 bf16 (4 VGPRs)
typedef float f32x4 __attribute__((ext_vector_type(4)));
typedef float f32x4n __attribute__((ext_vector_type(4))); // native clang vector for nt loads
typedef unsigned int u32x4 __attribute__((ext_vector_type(4)));

__device__ __forceinline__ unsigned int f2bf(float f) {
    unsigned int u = __builtin_bit_cast(unsigned int, f);
    return (u + 0x7fffu + ((u >> 16) & 1u)) >> 16;
}
// packed f32x2 -> bf16x2 via HW cvt (RNE, same bits as f2bf)
__device__ __forceinline__ unsigned int pk2bf(float lo, float hi) {
    unsigned int r;
    asm("v_cvt_pk_bf16_f32 %0, %1, %2" : "=v"(r) : "v"(lo), "v"(hi));
    return r;
}
__device__ __forceinline__ float bf_lo(unsigned int u) {
    return __builtin_bit_cast(float, u << 16);
}
__device__ __forceinline__ float bf_hi(unsigned int u) {
    return __builtin_bit_cast(float, u & 0xFFFF0000u);
}
// relu on 2 packed bf16: zero each 16-bit half whose sign bit is set
__device__ __forceinline__ unsigned int relu_pk(unsigned int w) {
    unsigned int keep = (~w) & 0x80008000u;
    unsigned int mask = keep - (keep >> 15);
    return w & mask;
}

// ---------------- bucket-sort CSR build ----------------
__global__ void init_cursor_kernel(int* __restrict__ cursor, int NB) {
    int i = blockIdx.x * blockDim.x + threadIdx.x;
    if (i < NB) cursor[i] = i * BPAD;
}

// bin edges into padded bucket regions; per-edge cursors in LDS, one global atomic per (block,bucket)
__global__ void bin_kernel(const int* __restrict__ src, const int* __restrict__ dst,
                           int* __restrict__ cursor, int* __restrict__ binned,
                           int E, int NB) {
    __shared__ int h[512];
    __shared__ int base[512];
    __shared__ int cur[512];
    const int tid = threadIdx.x;
    for (int i = tid; i < NB; i += 256) h[i] = 0;
    __syncthreads();

    const int E4 = E >> 2;
    const int beg4 = blockIdx.x * (CHUNK / 4);
    const int end4 = min(E4, beg4 + CHUNK / 4);
    const int4* dst4 = reinterpret_cast<const int4*>(dst);
    const int4* src4 = reinterpret_cast<const int4*>(src);
    const bool last = (blockIdx.x == gridDim.x - 1);

    for (int e4 = beg4 + tid; e4 < end4; e4 += 256) {
        int4 d = dst4[e4];
        atomicAdd(&h[d.x >> 8], 1);
        atomicAdd(&h[d.y >> 8], 1);
        atomicAdd(&h[d.z >> 8], 1);
        atomicAdd(&h[d.w >> 8], 1);
    }
    if (last) {
        for (int e = (E & ~3) + tid; e < E; e += 256)
            atomicAdd(&h[dst[e] >> 8], 1);
    }
    __syncthreads();
    for (int i = tid; i < NB; i += 256) {
        cur[i] = 0;
        if (h[i]) base[i] = atomicAdd(&cursor[i], h[i]);
    }
    __syncthreads();

    for (int e4 = beg4 + tid; e4 < end4; e4 += 256) {
        int4 d = dst4[e4];
        int4 s = src4[e4];
        int b, r, idx;
        b = d.x >> 8; r = atomicAdd(&cur[b], 1); idx = base[b] + r;
        if (idx < (b + 1) * BPAD) binned[idx] = s.x | ((d.x & 255) << 17);
        b = d.y >> 8; r = atomicAdd(&cur[b], 1); idx = base[b] + r;
        if (idx < (b + 1) * BPAD) binned[idx] = s.y | ((d.y & 255) << 17);
        b = d.z >> 8; r = atomicAdd(&cur[b], 1); idx = base[b] + r;
        if (idx < (b + 1) * BPAD) binned[idx] = s.z | ((d.z & 255) << 17);
        b = d.w >> 8; r = atomicAdd(&cur[b], 1); idx = base[b] + r;
        if (idx < (b + 1) * BPAD) binned[idx] = s.w | ((d.w & 255) << 17);
    }
    if (last) {
        for (int e = (E & ~3) + tid; e < E; e += 256) {
            int d = dst[e];
            int b = d >> 8;
            int r = atomicAdd(&cur[b], 1);
            int idx = base[b] + r;
            if (idx < (b + 1) * BPAD) binned[idx] = src[e] | ((d & 255) << 17);
        }
    }
}

// per-bucket (256 nodes) CSR finalize: row ranges, dinv, csr_src; per-edge atomics in LDS
__global__ void csr_bucket_kernel(const int* __restrict__ binned, const int* __restrict__ cursor,
                                  int2* __restrict__ row_range, int* __restrict__ csr_src,
                                  float* __restrict__ dinv, int N) {
    __shared__ int cnt[256];
    __shared__ int off[256];
    __shared__ int cur[256];
    const int k = blockIdx.x;
    const int t = threadIdx.x;
    cnt[t] = 0;
    __syncthreads();
    const int beg = k * BPAD;
    const int end = min(cursor[k], (k + 1) * BPAD);
    const int nv = (end - beg) & ~3;        // vectorizable count (beg is 16B-aligned)
    const int4* b4 = reinterpret_cast<const int4*>(binned + beg);

    for (int q = t; q * 4 < nv; q += 256) {
        int4 p = b4[q];
        atomicAdd(&cnt[p.x >> 17], 1);
        atomicAdd(&cnt[p.y >> 17], 1);
        atomicAdd(&cnt[p.z >> 17], 1);
        atomicAdd(&cnt[p.w >> 17], 1);
    }
    for (int e = beg + nv + t; e < end; e += 256)
        atomicAdd(&cnt[binned[e] >> 17], 1);
    __syncthreads();
    int v = cnt[t];
    off[t] = v;
    __syncthreads();
    #pragma unroll
    for (int o = 1; o < 256; o <<= 1) {
        int tv = (t >= o) ? off[t - o] : 0;
        __syncthreads();
        off[t] += tv;
        __syncthreads();
    }
    int ex = off[t] - v;
    int node = k * 256 + t;
    if (node < N) {
        row_range[node] = make_int2(beg + ex, beg + ex + v);
        dinv[node] = rsqrtf((float)(v + 1));   // +1 self-loop
    }
    cur[t] = ex;
    __syncthreads();
    for (int q = t; q * 4 < nv; q += 256) {
        int4 p = b4[q];
        int dl, r;
        dl = p.x >> 17; r = atomicAdd(&cur[dl], 1); csr_src[beg + r] = p.x & 0x1FFFF;
        dl = p.y >> 17; r = atomicAdd(&cur[dl], 1); csr_src[beg + r] = p.y & 0x1FFFF;
        dl = p.z >> 17; r = atomicAdd(&cur[dl], 1); csr_src[beg + r] = p.z & 0x1FFFF;
        dl = p.w >> 17; r = atomicAdd(&cur[dl], 1); csr_src[beg + r] = p.w & 0x1FFFF;
    }
    for (int e = beg + nv + t; e < end; e += 256) {
        int p = binned[e];
        int dl = p >> 17;
        int r = atomicAdd(&cur[dl], 1);
        csr_src[beg + r] = p & 0x1FFFF;
    }
}

// ---------------- weight pre-transpose to MFMA B-fragment layout ----------------
// WT[g*128 + col] (uint4 = 8 bf16) holds W[k(g*8+j)][col], j=0..7.
// PERM: storage k' -> true k = (k'>>3) + ((k'&7)<<4)  (layer 2: A cols are permuted)
template<bool PERM>
__global__ void convert_w_kernel(const float* __restrict__ W, uint4* __restrict__ WT, int K) {
    int i = blockIdx.x * blockDim.x + threadIdx.x;
    int ng = K >> 3;
    if (i >= ng * CH) return;
    int g = i >> 7;
    int col = i & 127;
    unsigned int h[8];
    #pragma unroll
    for (int j = 0; j < 8; ++j) {
        int kp = g * 8 + j;
        int k = PERM ? ((kp >> 3) + ((kp & 7) << 4)) : kp;
        h[j] = f2bf(W[(size_t)k * CH + col]);
    }
    uint4 v;
    v.x = h[0] | (h[1] << 16);
    v.y = h[2] | (h[3] << 16);
    v.z = h[4] | (h[5] << 16);
    v.w = h[6] | (h[7] << 16);
    WT[i] = v;
}

// ---------------- GEMM1: g1[M][128](bf16, permuted cols) = (x[M][512] @ W1) * dinv[row] ----------------
// Round-7 structure (1-deep register double-buffer, fully unrolled) with NON-TEMPORAL A loads
// (native clang vector type for the builtin): x is 205MB read-once data; nt (no-allocate)
// policy lets it stream via HBM instead of the slow L3-resident read path (round-6 counter
// row: hbm_gbps=220 -> x was L3-served at ~2TB/s).
// storage col' = l15*8 + n  (true col = n*16 + l15)
__launch_bounds__(256)
__global__ void gemm1_mfma_kernel(const float* __restrict__ A, const uint4* __restrict__ WT,
                                  const float* __restrict__ dinv, unsigned short* __restrict__ C,
                                  int M) {
    const int tid = threadIdx.x;
    const int wid = tid >> 6;
    const int lane = tid & 63;
    const int l15 = lane & 15;
    const int lg = lane >> 4;

    const int block_row = blockIdx.x * 128 + wid * 32;

    f32x4 acc[2][8];
    #pragma unroll
    for (int m = 0; m < 2; ++m)
        #pragma unroll
        for (int n = 0; n < 8; ++n)
            acc[m][n] = (f32x4){0.f, 0.f, 0.f, 0.f};

    const int arow0 = min(block_row + l15, M - 1);
    const int arow1 = min(block_row + 16 + l15, M - 1);
    const f32x4n* ap0 = reinterpret_cast<const f32x4n*>(A + (size_t)arow0 * IN_CH_K) + lg * 2;
    const f32x4n* ap1 = reinterpret_cast<const f32x4n*>(A + (size_t)arow1 * IN_CH_K) + lg * 2;
    const uint4* wp = WT + (size_t)lg * CH + l15;   // +4*CH per k-step; +16*n per frag

    // ---- prologue: load k-step 0 (non-temporal A) ----
    f32x4n a00 = __builtin_nontemporal_load(ap0);
    f32x4n a01 = __builtin_nontemporal_load(ap0 + 1);
    f32x4n a10 = __builtin_nontemporal_load(ap1);
    f32x4n a11 = __builtin_nontemporal_load(ap1 + 1);
    uint4 bw[8];
    #pragma unroll
    for (int n = 0; n < 8; ++n) bw[n] = wp[n * 16];

    #pragma unroll
    for (int ks = 0; ks < 16; ++ks) {
        // ---- issue next k-step's loads (A first: longest latency) ----
        f32x4n na00, na01, na10, na11;
        uint4 nbw[8];
        if (ks < 15) {
            const int o4 = (ks + 1) * 8;           // 32 floats = 8 float4 per k-step
            na00 = __builtin_nontemporal_load(ap0 + o4);
            na01 = __builtin_nontemporal_load(ap0 + o4 + 1);
            na10 = __builtin_nontemporal_load(ap1 + o4);
            na11 = __builtin_nontemporal_load(ap1 + o4 + 1);
            const uint4* nwp = wp + (size_t)(ks + 1) * 4 * CH;
            #pragma unroll
            for (int n = 0; n < 8; ++n) nbw[n] = nwp[n * 16];
        }

        // ---- convert current A to bf16 fragments ----
        uint4 pk0, pk1;
        pk0.x = pk2bf(a00[0], a00[1]);  pk0.y = pk2bf(a00[2], a00[3]);
        pk0.z = pk2bf(a01[0], a01[1]);  pk0.w = pk2bf(a01[2], a01[3]);
        pk1.x = pk2bf(a10[0], a10[1]);  pk1.y = pk2bf(a10[2], a10[3]);
        pk1.z = pk2bf(a11[0], a11[1]);  pk1.w = pk2bf(a11[2], a11[3]);
        s16x8 af0 = __builtin_bit_cast(s16x8, pk0);
        s16x8 af1 = __builtin_bit_cast(s16x8, pk1);

        // ---- MFMA on current buffers ----
        #pragma unroll
        for (int n = 0; n < 8; ++n) {
            s16x8 b = __builtin_bit_cast(s16x8, bw[n]);
            acc[0][n] = __builtin_amdgcn_mfma_f32_16x16x32_bf16(af0, b, acc[0][n], 0, 0, 0);
            acc[1][n] = __builtin_amdgcn_mfma_f32_16x16x32_bf16(af1, b, acc[1][n], 0, 0, 0);
        }

        // ---- rotate (statically renamed by full unroll) ----
        if (ks < 15) {
            a00 = na00; a01 = na01; a10 = na10; a11 = na11;
            #pragma unroll
            for (int n = 0; n < 8; ++n) bw[n] = nbw[n];
        }
    }

    #pragma unroll
    for (int m = 0; m < 2; ++m) {
        #pragma unroll
        for (int i = 0; i < 4; ++i) {
            int row = block_row + m * 16 + lg * 4 + i;
            if (row < M) {
                float s = dinv[row];
                uint4 v;
                v.x = pk2bf(acc[m][0][i] * s, acc[m][1][i] * s);
                v.y = pk2bf(acc[m][2][i] * s, acc[m][3][i] * s);
                v.z = pk2bf(acc[m][4][i] * s, acc[m][5][i] * s);
                v.w = pk2bf(acc[m][6][i] * s, acc[m][7][i] * s);
                *reinterpret_cast<uint4*>(&C[(size_t)row * CH + l15 * 8]) = v;
            }
        }
    }
}

// ---------------- GEMM2: g2 = (relu(a1)[M][128] @ W2) * dinv[row], all bf16 permuted ----------------
__launch_bounds__(256)
__global__ void gemm2_mfma_kernel(const unsigned short* __restrict__ A, const uint4* __restrict__ WT,
                                  const float* __restrict__ dinv, unsigned short* __restrict__ C,
                                  int M) {
    const int tid = threadIdx.x;
    const int wid = tid >> 6;
    const int lane = tid & 63;
    const int l15 = lane & 15;
    const int lg = lane >> 4;

    const int block_row = blockIdx.x * 128 + wid * 32;

    f32x4 acc[2][8];
    #pragma unroll
    for (int m = 0; m < 2; ++m)
        #pragma unroll
        for (int n = 0; n < 8; ++n)
            acc[m][n] = (f32x4){0.f, 0.f, 0.f, 0.f};

    int arow0 = min(block_row + l15, M - 1);
    int arow1 = min(block_row + 16 + l15, M - 1);
    const uint4* ap0 = reinterpret_cast<const uint4*>(A + (size_t)arow0 * CH);
    const uint4* ap1 = reinterpret_cast<const uint4*>(A + (size_t)arow1 * CH);

    #pragma unroll
    for (int k0 = 0; k0 < CH; k0 += 32) {
        const int fi = (k0 >> 3) + lg;
        uint4 r0 = ap0[fi];
        uint4 r1 = ap1[fi];
        r0.x = relu_pk(r0.x); r0.y = relu_pk(r0.y); r0.z = relu_pk(r0.z); r0.w = relu_pk(r0.w);
        r1.x = relu_pk(r1.x); r1.y = relu_pk(r1.y); r1.z = relu_pk(r1.z); r1.w = relu_pk(r1.w);
        s16x8 a0 = __builtin_bit_cast(s16x8, r0);
        s16x8 a1 = __builtin_bit_cast(s16x8, r1);
        #pragma unroll
        for (int n = 0; n < 8; ++n) {
            uint4 bv = WT[(size_t)fi * CH + n * 16 + l15];
            s16x8 b = __builtin_bit_cast(s16x8, bv);
            acc[0][n] = __builtin_amdgcn_mfma_f32_16x16x32_bf16(a0, b, acc[0][n], 0, 0, 0);
            acc[1][n] = __builtin_amdgcn_mfma_f32_16x16x32_bf16(a1, b, acc[1][n], 0, 0, 0);
        }
    }

    #pragma unroll
    for (int m = 0; m < 2; ++m) {
        #pragma unroll
        for (int i = 0; i < 4; ++i) {
            int row = block_row + m * 16 + lg * 4 + i;
            if (row < M) {
                float s = dinv[row];
                uint4 v;
                v.x = pk2bf(acc[m][0][i] * s, acc[m][1][i] * s);
                v.y = pk2bf(acc[m][2][i] * s, acc[m][3][i] * s);
                v.z = pk2bf(acc[m][4][i] * s, acc[m][5][i] * s);
                v.w = pk2bf(acc[m][6][i] * s, acc[m][7][i] * s);
                *reinterpret_cast<uint4*>(&C[(size_t)row * CH + l15 * 8]) = v;
            }
        }
    }
}

// ---------------- aggregation: out[d] = dinv[d]*(g[d] + sum g[src]) + bias ----------------
// g is bf16 permuted-col [node][128]; one wave per node, 1 uint (2 bf16) per lane.
// 8-deep software-pipelined gather: next batch's indices load while current gathers fly.
#define GATHER(cc) g[(size_t)__builtin_amdgcn_readfirstlane(cc) * 64 + lane]
template<bool OUT_BF16>
__launch_bounds__(256)
__global__ void aggregate_kernel(const unsigned int* __restrict__ g, const int2* __restrict__ row_range,
                                 const int* __restrict__ csr_src, const float* __restrict__ dinv,
                                 const float* __restrict__ bias, void* __restrict__ outp, int N) {
    const int gtid = blockIdx.x * blockDim.x + threadIdx.x;
    const int node = gtid >> 6;
    if (node >= N) return;
    const int lane = threadIdx.x & 63;

    unsigned int su = g[(size_t)node * 64 + lane];   // self-loop term
    const int2 rr = row_range[node];
    float ax = bf_lo(su);
    float ay = bf_hi(su);

    int j = rr.x;
    const int end = rr.y;

    if (j + 8 <= end) {
        int c0 = csr_src[j], c1 = csr_src[j+1], c2 = csr_src[j+2], c3 = csr_src[j+3];
        int c4 = csr_src[j+4], c5 = csr_src[j+5], c6 = csr_src[j+6], c7 = csr_src[j+7];
        j += 8;
        while (j + 8 <= end) {
            int n0 = csr_src[j], n1 = csr_src[j+1], n2 = csr_src[j+2], n3 = csr_src[j+3];
            int n4 = csr_src[j+4], n5 = csr_src[j+5], n6 = csr_src[j+6], n7 = csr_src[j+7];
            j += 8;
            unsigned int u0 = GATHER(c0), u1 = GATHER(c1), u2 = GATHER(c2), u3 = GATHER(c3);
            unsigned int u4 = GATHER(c4), u5 = GATHER(c5), u6 = GATHER(c6), u7 = GATHER(c7);
            ax += ((bf_lo(u0) + bf_lo(u1)) + (bf_lo(u2) + bf_lo(u3)))
                + ((bf_lo(u4) + bf_lo(u5)) + (bf_lo(u6) + bf_lo(u7)));
            ay += ((bf_hi(u0) + bf_hi(u1)) + (bf_hi(u2) + bf_hi(u3)))
                + ((bf_hi(u4) + bf_hi(u5)) + (bf_hi(u6) + bf_hi(u7)));
            c0 = n0; c1 = n1; c2 = n2; c3 = n3;
            c4 = n4; c5 = n5; c6 = n6; c7 = n7;
        }
        unsigned int u0 = GATHER(c0), u1 = GATHER(c1), u2 = GATHER(c2), u3 = GATHER(c3);
        unsigned int u4 = GATHER(c4), u5 = GATHER(c5), u6 = GATHER(c6), u7 = GATHER(c7);
        ax += ((bf_lo(u0) + bf_lo(u1)) + (bf_lo(u2) + bf_lo(u3)))
            + ((bf_lo(u4) + bf_lo(u5)) + (bf_lo(u6) + bf_lo(u7)));
        ay += ((bf_hi(u0) + bf_hi(u1)) + (bf_hi(u2) + bf_hi(u3)))
            + ((bf_hi(u4) + bf_hi(u5)) + (bf_hi(u6) + bf_hi(u7)));
    }
    for (; j + 2 <= end; j += 2) {
        int c0 = csr_src[j], c1 = csr_src[j+1];
        unsigned int u0 = GATHER(c0), u1 = GATHER(c1);
        ax += bf_lo(u0) + bf_lo(u1);
        ay += bf_hi(u0) + bf_hi(u1);
    }
    if (j < end) {
        int c0 = csr_src[j];
        unsigned int u0 = GATHER(c0);
        ax += bf_lo(u0);
        ay += bf_hi(u0);
    }

    const int cp0 = lane << 1;
    const int cp1 = cp0 | 1;
    const int c0 = (cp0 >> 3) + ((cp0 & 7) << 4);    // true cols
    const int c1 = (cp1 >> 3) + ((cp1 & 7) << 4);
    const float di = dinv[node];
    float ox = di * ax + bias[c0];
    float oy = di * ay + bias[c1];
    if (OUT_BF16) {
        ((unsigned int*)outp)[(size_t)node * 64 + lane] = pk2bf(ox, oy);
    } else {
        float* o = (float*)outp + (size_t)node * CH;
        o[c0] = ox;
        o[c1] = oy;
    }
}

extern "C" void kernel_launch(void* const* d_in, const int* in_sizes, int n_in,
                              void* d_out, int out_size, void* d_ws, size_t ws_size,
                              hipStream_t stream) {
    const float* x  = (const float*)d_in[0];
    const int*   ei = (const int*)d_in[1];
    const float* W1 = (const float*)d_in[2];
    const float* b1 = (const float*)d_in[3];
    const float* W2 = (const float*)d_in[4];
    const float* b2 = (const float*)d_in[5];
    float* out = (float*)d_out;

    const int N = in_sizes[0] / IN_CH_K;       // 100000
    const int E = in_sizes[1] / 2;             // 1600000
    const int* e_src = ei;
    const int* e_dst = ei + E;

    const int NB = (N + 255) >> 8;             // 391 coarse buckets
    const int NCHUNK = (E + CHUNK - 1) / CHUNK;

    char* w = (char*)d_ws;
    auto alloc = [&](size_t bytes) {
        char* p = w;
        w += (bytes + 255) & ~(size_t)255;
        return p;
    };
    int*   cursor    = (int*)  alloc((size_t)NB * 4);
    int2*  row_range = (int2*) alloc((size_t)N * 8);
    float* dinv      = (float*)alloc((size_t)N * 4);
    int*   csr_src   = (int*)  alloc((size_t)NB * BPAD * 4);
    uint4* w1t       = (uint4*)alloc((size_t)(IN_CH_K / 8) * CH * 16);
    uint4* w2t       = (uint4*)alloc((size_t)(CH / 8) * CH * 16);
    unsigned short* gbuf = (unsigned short*)alloc((size_t)N * CH * 2);  // g1 / g2
    unsigned short* abuf = (unsigned short*)alloc((size_t)N * CH * 2);  // a1
    int* binned = (int*)gbuf;   // aliases gbuf (8 MB < 25.6 MB): dead before gemm1 writes

    // ---- CSR build (padded bucket sort) + weight conversion ----
    init_cursor_kernel<<<(NB + 255) / 256, 256, 0, stream>>>(cursor, NB);
    bin_kernel<<<NCHUNK, 256, 0, stream>>>(e_src, e_dst, cursor, binned, E, NB);
    csr_bucket_kernel<<<NB, 256, 0, stream>>>(binned, cursor, row_range, csr_src, dinv, N);
    convert_w_kernel<false><<<(IN_CH_K / 8 * CH + 255) / 256, 256, 0, stream>>>(W1, w1t, IN_CH_K);
    convert_w_kernel<true><<<(CH / 8 * CH + 255) / 256, 256, 0, stream>>>(W2, w2t, CH);

    const int gemm_grid = (N + 127) / 128;
    const int agg_grid = (N * 64 + 255) / 256;

    // ---- layer 1 ----
    gemm1_mfma_kernel<<<gemm_grid, 256, 0, stream>>>(x, w1t, dinv, gbuf, N);
    aggregate_kernel<true><<<agg_grid, 256, 0, stream>>>((const unsigned int*)gbuf, row_range,
                                                         csr_src, dinv, b1, abuf, N);

    // ---- layer 2 ----
    gemm2_mfma_kernel<<<gemm_grid, 256, 0, stream>>>(abuf, w2t, dinv, gbuf, N);
    aggregate_kernel<false><<<agg_grid, 256, 0, stream>>>((const unsigned int*)gbuf, row_range,
                                                          csr_src, dinv, b2, out, N);
}

// Round 14
// 276.915 us; speedup vs baseline: 1.1479x; 1.0147x over previous
//
#include <hip/hip_runtime.h>
#include <hip/hip_bf16.h>

#define CH 128          // HID_CH == OUT_CH == 128
#define IN_CH_K 512
#define CHUNK 2048      // edges per bucket-sort block (782 blocks -> ~3/CU)
#define BPAD 5120       // padded per-bucket capacity (expect ~4096, 16-sigma margin)

typedef short s16x8 __attribute__((ext_vector_type(8)));   // 8 bf16 (4 VGPRs)
typedef float f32x4 __attribute__((ext_vector_type(4)));

__device__ __forceinline__ unsigned int f2bf(float f) {
    unsigned int u = __builtin_bit_cast(unsigned int, f);
    return (u + 0x7fffu + ((u >> 16) & 1u)) >> 16;
}
// packed f32x2 -> bf16x2 via HW cvt (RNE, same bits as f2bf)
__device__ __forceinline__ unsigned int pk2bf(float lo, float hi) {
    unsigned int r;
    asm("v_cvt_pk_bf16_f32 %0, %1, %2" : "=v"(r) : "v"(lo), "v"(hi));
    return r;
}
__device__ __forceinline__ float bf_lo(unsigned int u) {
    return __builtin_bit_cast(float, u << 16);
}
__device__ __forceinline__ float bf_hi(unsigned int u) {
    return __builtin_bit_cast(float, u & 0xFFFF0000u);
}
// relu on 2 packed bf16: zero each 16-bit half whose sign bit is set
__device__ __forceinline__ unsigned int relu_pk(unsigned int w) {
    unsigned int keep = (~w) & 0x80008000u;
    unsigned int mask = keep - (keep >> 15);
    return w & mask;
}

// ---------------- bucket-sort CSR build ----------------
__global__ void init_cursor_kernel(int* __restrict__ cursor, int NB) {
    int i = blockIdx.x * blockDim.x + threadIdx.x;
    if (i < NB) cursor[i] = i * BPAD;
}

// bin edges into padded bucket regions; per-edge cursors in LDS, one global atomic per (block,bucket)
__global__ void bin_kernel(const int* __restrict__ src, const int* __restrict__ dst,
                           int* __restrict__ cursor, int* __restrict__ binned,
                           int E, int NB) {
    __shared__ int h[512];
    __shared__ int base[512];
    __shared__ int cur[512];
    const int tid = threadIdx.x;
    for (int i = tid; i < NB; i += 256) h[i] = 0;
    __syncthreads();

    const int E4 = E >> 2;
    const int beg4 = blockIdx.x * (CHUNK / 4);
    const int end4 = min(E4, beg4 + CHUNK / 4);
    const int4* dst4 = reinterpret_cast<const int4*>(dst);
    const int4* src4 = reinterpret_cast<const int4*>(src);
    const bool last = (blockIdx.x == gridDim.x - 1);

    for (int e4 = beg4 + tid; e4 < end4; e4 += 256) {
        int4 d = dst4[e4];
        atomicAdd(&h[d.x >> 8], 1);
        atomicAdd(&h[d.y >> 8], 1);
        atomicAdd(&h[d.z >> 8], 1);
        atomicAdd(&h[d.w >> 8], 1);
    }
    if (last) {
        for (int e = (E & ~3) + tid; e < E; e += 256)
            atomicAdd(&h[dst[e] >> 8], 1);
    }
    __syncthreads();
    for (int i = tid; i < NB; i += 256) {
        cur[i] = 0;
        if (h[i]) base[i] = atomicAdd(&cursor[i], h[i]);
    }
    __syncthreads();

    for (int e4 = beg4 + tid; e4 < end4; e4 += 256) {
        int4 d = dst4[e4];
        int4 s = src4[e4];
        int b, r, idx;
        b = d.x >> 8; r = atomicAdd(&cur[b], 1); idx = base[b] + r;
        if (idx < (b + 1) * BPAD) binned[idx] = s.x | ((d.x & 255) << 17);
        b = d.y >> 8; r = atomicAdd(&cur[b], 1); idx = base[b] + r;
        if (idx < (b + 1) * BPAD) binned[idx] = s.y | ((d.y & 255) << 17);
        b = d.z >> 8; r = atomicAdd(&cur[b], 1); idx = base[b] + r;
        if (idx < (b + 1) * BPAD) binned[idx] = s.z | ((d.z & 255) << 17);
        b = d.w >> 8; r = atomicAdd(&cur[b], 1); idx = base[b] + r;
        if (idx < (b + 1) * BPAD) binned[idx] = s.w | ((d.w & 255) << 17);
    }
    if (last) {
        for (int e = (E & ~3) + tid; e < E; e += 256) {
            int d = dst[e];
            int b = d >> 8;
            int r = atomicAdd(&cur[b], 1);
            int idx = base[b] + r;
            if (idx < (b + 1) * BPAD) binned[idx] = src[e] | ((d & 255) << 17);
        }
    }
}

// per-bucket (256 nodes) CSR finalize: row ranges, dinv, csr_src; per-edge atomics in LDS
__global__ void csr_bucket_kernel(const int* __restrict__ binned, const int* __restrict__ cursor,
                                  int2* __restrict__ row_range, int* __restrict__ csr_src,
                                  float* __restrict__ dinv, int N) {
    __shared__ int cnt[256];
    __shared__ int off[256];
    __shared__ int cur[256];
    const int k = blockIdx.x;
    const int t = threadIdx.x;
    cnt[t] = 0;
    __syncthreads();
    const int beg = k * BPAD;
    const int end = min(cursor[k], (k + 1) * BPAD);
    const int nv = (end - beg) & ~3;        // vectorizable count (beg is 16B-aligned)
    const int4* b4 = reinterpret_cast<const int4*>(binned + beg);

    for (int q = t; q * 4 < nv; q += 256) {
        int4 p = b4[q];
        atomicAdd(&cnt[p.x >> 17], 1);
        atomicAdd(&cnt[p.y >> 17], 1);
        atomicAdd(&cnt[p.z >> 17], 1);
        atomicAdd(&cnt[p.w >> 17], 1);
    }
    for (int e = beg + nv + t; e < end; e += 256)
        atomicAdd(&cnt[binned[e] >> 17], 1);
    __syncthreads();
    int v = cnt[t];
    off[t] = v;
    __syncthreads();
    #pragma unroll
    for (int o = 1; o < 256; o <<= 1) {
        int tv = (t >= o) ? off[t - o] : 0;
        __syncthreads();
        off[t] += tv;
        __syncthreads();
    }
    int ex = off[t] - v;
    int node = k * 256 + t;
    if (node < N) {
        row_range[node] = make_int2(beg + ex, beg + ex + v);
        dinv[node] = rsqrtf((float)(v + 1));   // +1 self-loop
    }
    cur[t] = ex;
    __syncthreads();
    for (int q = t; q * 4 < nv; q += 256) {
        int4 p = b4[q];
        int dl, r;
        dl = p.x >> 17; r = atomicAdd(&cur[dl], 1); csr_src[beg + r] = p.x & 0x1FFFF;
        dl = p.y >> 17; r = atomicAdd(&cur[dl], 1); csr_src[beg + r] = p.y & 0x1FFFF;
        dl = p.z >> 17; r = atomicAdd(&cur[dl], 1); csr_src[beg + r] = p.z & 0x1FFFF;
        dl = p.w >> 17; r = atomicAdd(&cur[dl], 1); csr_src[beg + r] = p.w & 0x1FFFF;
    }
    for (int e = beg + nv + t; e < end; e += 256) {
        int p = binned[e];
        int dl = p >> 17;
        int r = atomicAdd(&cur[dl], 1);
        csr_src[beg + r] = p & 0x1FFFF;
    }
}

// ---------------- weight pre-transpose to MFMA B-fragment layout ----------------
// WT[g*128 + col] (uint4 = 8 bf16) holds W[k(g*8+j)][col], j=0..7.
// PERM: storage k' -> true k = (k'>>3) + ((k'&7)<<4)  (layer 2: A cols are permuted)
template<bool PERM>
__global__ void convert_w_kernel(const float* __restrict__ W, uint4* __restrict__ WT, int K) {
    int i = blockIdx.x * blockDim.x + threadIdx.x;
    int ng = K >> 3;
    if (i >= ng * CH) return;
    int g = i >> 7;
    int col = i & 127;
    unsigned int h[8];
    #pragma unroll
    for (int j = 0; j < 8; ++j) {
        int kp = g * 8 + j;
        int k = PERM ? ((kp >> 3) + ((kp & 7) << 4)) : kp;
        h[j] = f2bf(W[(size_t)k * CH + col]);
    }
    uint4 v;
    v.x = h[0] | (h[1] << 16);
    v.y = h[2] | (h[3] << 16);
    v.z = h[4] | (h[5] << 16);
    v.w = h[6] | (h[7] << 16);
    WT[i] = v;
}

// ---------------- GEMM1: g1[M][128](bf16, permuted cols) = (x[M][512] @ W1) * dinv[row] ----------------
// Async-DMA staged: x is read via global_load_lds (width 16) -- the direct-to-LDS path that
// holds in-flight data at ZERO VGPR cost (16 x 1KB outstanding per wave; 128KB/CU at 8 waves).
// LDS is granule-major [64 blocks][32 rows x 32B f32] with 16B pad per 1KB block; the pad makes
// the compute-phase ds_read_b128 pairs exactly 2-way bank-aliased (free, per G4/m136).
// Each wave: stage granules wid*16..+15 (per-lane global addr, linear LDS dest), then compute
// 2 m-frags x 2 n-frags (n = wid*2+{0,1}) over all 16 k-steps. Output layout unchanged
// (storage col' = l15*8 + n; true col = n*16 + l15); u32 stores per (row, n-pair).
#define G1B 1040   // bytes per granule block: 32 rows * 32B + 16B pad
__launch_bounds__(256, 2)
__global__ void gemm1_mfma_kernel(const float* __restrict__ A, const uint4* __restrict__ WT,
                                  const float* __restrict__ dinv, unsigned short* __restrict__ C,
                                  int M) {
    __shared__ unsigned char lds_raw[64 * G1B];   // 65 KB -> 2 blocks/CU

    const int tid = threadIdx.x;
    const int wid = tid >> 6;
    const int lane = tid & 63;
    const int block_row = blockIdx.x * 32;

    // ---- stage via async DMA ----
    {
        int grow = block_row + (lane >> 1);
        if (grow >= M) grow = M - 1;
        const float* gbase = A + (size_t)grow * IN_CH_K + (lane & 1) * 4;
        #pragma unroll
        for (int i = 0; i < 16; ++i) {
            const int g = wid * 16 + i;
            const float* gp = gbase + g * 8;             // granule g: 8 floats = 32B
            void* lp = (void*)&lds_raw[g * G1B];          // + lane*16 implicit
            __builtin_amdgcn_global_load_lds(
                (const __attribute__((address_space(1))) void*)gp,
                (__attribute__((address_space(3))) void*)lp, 16, 0, 0);
        }
    }
    __syncthreads();   // compiler drains vmcnt before s_barrier

    const int l15 = lane & 15;
    const int lg = lane >> 4;
    const int ncol = wid * 2;   // this wave's global n-frag base (0,2,4,6)

    f32x4 acc[2][2];
    #pragma unroll
    for (int m = 0; m < 2; ++m)
        #pragma unroll
        for (int n = 0; n < 2; ++n)
            acc[m][n] = (f32x4){0.f, 0.f, 0.f, 0.f};

    #pragma unroll 4
    for (int ks = 0; ks < 16; ++ks) {
        const int g = ks * 4 + lg;
        uint4 b0v = WT[(size_t)g * CH + ncol * 16 + l15];
        uint4 b1v = WT[(size_t)g * CH + (ncol + 1) * 16 + l15];
        s16x8 b0 = __builtin_bit_cast(s16x8, b0v);
        s16x8 b1 = __builtin_bit_cast(s16x8, b1v);

        #pragma unroll
        for (int m = 0; m < 2; ++m) {
            const unsigned abase = (unsigned)(g * G1B + (m * 16 + l15) * 32);
            f32x4 fa0 = *reinterpret_cast<const f32x4*>(&lds_raw[abase]);
            f32x4 fa1 = *reinterpret_cast<const f32x4*>(&lds_raw[abase + 16]);
            uint4 pk;
            pk.x = pk2bf(fa0[0], fa0[1]);
            pk.y = pk2bf(fa0[2], fa0[3]);
            pk.z = pk2bf(fa1[0], fa1[1]);
            pk.w = pk2bf(fa1[2], fa1[3]);
            s16x8 af = __builtin_bit_cast(s16x8, pk);
            acc[m][0] = __builtin_amdgcn_mfma_f32_16x16x32_bf16(af, b0, acc[m][0], 0, 0, 0);
            acc[m][1] = __builtin_amdgcn_mfma_f32_16x16x32_bf16(af, b1, acc[m][1], 0, 0, 0);
        }
    }

    // ---- epilogue: D[row=lg*4+i][col=l15] per frag; scale; permuted bf16 u32 store ----
    #pragma unroll
    for (int m = 0; m < 2; ++m) {
        #pragma unroll
        for (int i = 0; i < 4; ++i) {
            int row = block_row + m * 16 + lg * 4 + i;
            if (row < M) {
                float s = dinv[row];
                unsigned pk = pk2bf(acc[m][0][i] * s, acc[m][1][i] * s);
                *reinterpret_cast<unsigned*>(&C[(size_t)row * CH + l15 * 8 + ncol]) = pk;
            }
        }
    }
}

// ---------------- GEMM2: g2 = (relu(a1)[M][128] @ W2) * dinv[row], all bf16 permuted ----------------
__launch_bounds__(256)
__global__ void gemm2_mfma_kernel(const unsigned short* __restrict__ A, const uint4* __restrict__ WT,
                                  const float* __restrict__ dinv, unsigned short* __restrict__ C,
                                  int M) {
    const int tid = threadIdx.x;
    const int wid = tid >> 6;
    const int lane = tid & 63;
    const int l15 = lane & 15;
    const int lg = lane >> 4;

    const int block_row = blockIdx.x * 128 + wid * 32;

    f32x4 acc[2][8];
    #pragma unroll
    for (int m = 0; m < 2; ++m)
        #pragma unroll
        for (int n = 0; n < 8; ++n)
            acc[m][n] = (f32x4){0.f, 0.f, 0.f, 0.f};

    int arow0 = min(block_row + l15, M - 1);
    int arow1 = min(block_row + 16 + l15, M - 1);
    const uint4* ap0 = reinterpret_cast<const uint4*>(A + (size_t)arow0 * CH);
    const uint4* ap1 = reinterpret_cast<const uint4*>(A + (size_t)arow1 * CH);

    #pragma unroll
    for (int k0 = 0; k0 < CH; k0 += 32) {
        const int fi = (k0 >> 3) + lg;
        uint4 r0 = ap0[fi];
        uint4 r1 = ap1[fi];
        r0.x = relu_pk(r0.x); r0.y = relu_pk(r0.y); r0.z = relu_pk(r0.z); r0.w = relu_pk(r0.w);
        r1.x = relu_pk(r1.x); r1.y = relu_pk(r1.y); r1.z = relu_pk(r1.z); r1.w = relu_pk(r1.w);
        s16x8 a0 = __builtin_bit_cast(s16x8, r0);
        s16x8 a1 = __builtin_bit_cast(s16x8, r1);
        #pragma unroll
        for (int n = 0; n < 8; ++n) {
            uint4 bv = WT[(size_t)fi * CH + n * 16 + l15];
            s16x8 b = __builtin_bit_cast(s16x8, bv);
            acc[0][n] = __builtin_amdgcn_mfma_f32_16x16x32_bf16(a0, b, acc[0][n], 0, 0, 0);
            acc[1][n] = __builtin_amdgcn_mfma_f32_16x16x32_bf16(a1, b, acc[1][n], 0, 0, 0);
        }
    }

    #pragma unroll
    for (int m = 0; m < 2; ++m) {
        #pragma unroll
        for (int i = 0; i < 4; ++i) {
            int row = block_row + m * 16 + lg * 4 + i;
            if (row < M) {
                float s = dinv[row];
                uint4 v;
                v.x = pk2bf(acc[m][0][i] * s, acc[m][1][i] * s);
                v.y = pk2bf(acc[m][2][i] * s, acc[m][3][i] * s);
                v.z = pk2bf(acc[m][4][i] * s, acc[m][5][i] * s);
                v.w = pk2bf(acc[m][6][i] * s, acc[m][7][i] * s);
                *reinterpret_cast<uint4*>(&C[(size_t)row * CH + l15 * 8]) = v;
            }
        }
    }
}

// ---------------- aggregation: out[d] = dinv[d]*(g[d] + sum g[src]) + bias ----------------
// g is bf16 permuted-col [node][128]; one wave per node, 1 uint (2 bf16) per lane.
// 8-deep software-pipelined gather: next batch's indices load while current gathers fly.
#define GATHER(cc) g[(size_t)__builtin_amdgcn_readfirstlane(cc) * 64 + lane]
template<bool OUT_BF16>
__launch_bounds__(256)
__global__ void aggregate_kernel(const unsigned int* __restrict__ g, const int2* __restrict__ row_range,
                                 const int* __restrict__ csr_src, const float* __restrict__ dinv,
                                 const float* __restrict__ bias, void* __restrict__ outp, int N) {
    const int gtid = blockIdx.x * blockDim.x + threadIdx.x;
    const int node = gtid >> 6;
    if (node >= N) return;
    const int lane = threadIdx.x & 63;

    unsigned int su = g[(size_t)node * 64 + lane];   // self-loop term
    const int2 rr = row_range[node];
    float ax = bf_lo(su);
    float ay = bf_hi(su);

    int j = rr.x;
    const int end = rr.y;

    if (j + 8 <= end) {
        int c0 = csr_src[j], c1 = csr_src[j+1], c2 = csr_src[j+2], c3 = csr_src[j+3];
        int c4 = csr_src[j+4], c5 = csr_src[j+5], c6 = csr_src[j+6], c7 = csr_src[j+7];
        j += 8;
        while (j + 8 <= end) {
            int n0 = csr_src[j], n1 = csr_src[j+1], n2 = csr_src[j+2], n3 = csr_src[j+3];
            int n4 = csr_src[j+4], n5 = csr_src[j+5], n6 = csr_src[j+6], n7 = csr_src[j+7];
            j += 8;
            unsigned int u0 = GATHER(c0), u1 = GATHER(c1), u2 = GATHER(c2), u3 = GATHER(c3);
            unsigned int u4 = GATHER(c4), u5 = GATHER(c5), u6 = GATHER(c6), u7 = GATHER(c7);
            ax += ((bf_lo(u0) + bf_lo(u1)) + (bf_lo(u2) + bf_lo(u3)))
                + ((bf_lo(u4) + bf_lo(u5)) + (bf_lo(u6) + bf_lo(u7)));
            ay += ((bf_hi(u0) + bf_hi(u1)) + (bf_hi(u2) + bf_hi(u3)))
                + ((bf_hi(u4) + bf_hi(u5)) + (bf_hi(u6) + bf_hi(u7)));
            c0 = n0; c1 = n1; c2 = n2; c3 = n3;
            c4 = n4; c5 = n5; c6 = n6; c7 = n7;
        }
        unsigned int u0 = GATHER(c0), u1 = GATHER(c1), u2 = GATHER(c2), u3 = GATHER(c3);
        unsigned int u4 = GATHER(c4), u5 = GATHER(c5), u6 = GATHER(c6), u7 = GATHER(c7);
        ax += ((bf_lo(u0) + bf_lo(u1)) + (bf_lo(u2) + bf_lo(u3)))
            + ((bf_lo(u4) + bf_lo(u5)) + (bf_lo(u6) + bf_lo(u7)));
        ay += ((bf_hi(u0) + bf_hi(u1)) + (bf_hi(u2) + bf_hi(u3)))
            + ((bf_hi(u4) + bf_hi(u5)) + (bf_hi(u6) + bf_hi(u7)));
    }
    for (; j + 2 <= end; j += 2) {
        int c0 = csr_src[j], c1 = csr_src[j+1];
        unsigned int u0 = GATHER(c0), u1 = GATHER(c1);
        ax += bf_lo(u0) + bf_lo(u1);
        ay += bf_hi(u0) + bf_hi(u1);
    }
    if (j < end) {
        int c0 = csr_src[j];
        unsigned int u0 = GATHER(c0);
        ax += bf_lo(u0);
        ay += bf_hi(u0);
    }

    const int cp0 = lane << 1;
    const int cp1 = cp0 | 1;
    const int c0 = (cp0 >> 3) + ((cp0 & 7) << 4);    // true cols
    const int c1 = (cp1 >> 3) + ((cp1 & 7) << 4);
    const float di = dinv[node];
    float ox = di * ax + bias[c0];
    float oy = di * ay + bias[c1];
    if (OUT_BF16) {
        ((unsigned int*)outp)[(size_t)node * 64 + lane] = pk2bf(ox, oy);
    } else {
        float* o = (float*)outp + (size_t)node * CH;
        o[c0] = ox;
        o[c1] = oy;
    }
}

extern "C" void kernel_launch(void* const* d_in, const int* in_sizes, int n_in,
                              void* d_out, int out_size, void* d_ws, size_t ws_size,
                              hipStream_t stream) {
    const float* x  = (const float*)d_in[0];
    const int*   ei = (const int*)d_in[1];
    const float* W1 = (const float*)d_in[2];
    const float* b1 = (const float*)d_in[3];
    const float* W2 = (const float*)d_in[4];
    const float* b2 = (const float*)d_in[5];
    float* out = (float*)d_out;

    const int N = in_sizes[0] / IN_CH_K;       // 100000
    const int E = in_sizes[1] / 2;             // 1600000
    const int* e_src = ei;
    const int* e_dst = ei + E;

    const int NB = (N + 255) >> 8;             // 391 coarse buckets
    const int NCHUNK = (E + CHUNK - 1) / CHUNK;

    char* w = (char*)d_ws;
    auto alloc = [&](size_t bytes) {
        char* p = w;
        w += (bytes + 255) & ~(size_t)255;
        return p;
    };
    int*   cursor    = (int*)  alloc((size_t)NB * 4);
    int2*  row_range = (int2*) alloc((size_t)N * 8);
    float* dinv      = (float*)alloc((size_t)N * 4);
    int*   csr_src   = (int*)  alloc((size_t)NB * BPAD * 4);
    uint4* w1t       = (uint4*)alloc((size_t)(IN_CH_K / 8) * CH * 16);
    uint4* w2t       = (uint4*)alloc((size_t)(CH / 8) * CH * 16);
    unsigned short* gbuf = (unsigned short*)alloc((size_t)N * CH * 2);  // g1 / g2
    unsigned short* abuf = (unsigned short*)alloc((size_t)N * CH * 2);  // a1
    int* binned = (int*)gbuf;   // aliases gbuf (8 MB < 25.6 MB): dead before gemm1 writes

    // ---- CSR build (padded bucket sort) + weight conversion ----
    init_cursor_kernel<<<(NB + 255) / 256, 256, 0, stream>>>(cursor, NB);
    bin_kernel<<<NCHUNK, 256, 0, stream>>>(e_src, e_dst, cursor, binned, E, NB);
    csr_bucket_kernel<<<NB, 256, 0, stream>>>(binned, cursor, row_range, csr_src, dinv, N);
    convert_w_kernel<false><<<(IN_CH_K / 8 * CH + 255) / 256, 256, 0, stream>>>(W1, w1t, IN_CH_K);
    convert_w_kernel<true><<<(CH / 8 * CH + 255) / 256, 256, 0, stream>>>(W2, w2t, CH);

    const int gemm1_grid = (N + 31) / 32;      // 32 rows per block (async-DMA staged)
    const int gemm2_grid = (N + 127) / 128;
    const int agg_grid = (N * 64 + 255) / 256;

    // ---- layer 1 ----
    gemm1_mfma_kernel<<<gemm1_grid, 256, 0, stream>>>(x, w1t, dinv, gbuf, N);
    aggregate_kernel<true><<<agg_grid, 256, 0, stream>>>((const unsigned int*)gbuf, row_range,
                                                         csr_src, dinv, b1, abuf, N);

    // ---- layer 2 ----
    gemm2_mfma_kernel<<<gemm2_grid, 256, 0, stream>>>(abuf, w2t, dinv, gbuf, N);
    aggregate_kernel<false><<<agg_grid, 256, 0, stream>>>((const unsigned int*)gbuf, row_range,
                                                          csr_src, dinv, b2, out, N);
}